// Round 17
// baseline (78.209 us; speedup 1.0000x reference)
//
#include <hip/hip_runtime.h>

#define B 128
#define S 512
#define T 64

typedef short bf16x8 __attribute__((ext_vector_type(8)));
typedef float f32x4 __attribute__((ext_vector_type(4)));
typedef _Float16 h2 __attribute__((ext_vector_type(2)));

__device__ __forceinline__ float rdlane(float v, int l) {
    return __int_as_float(__builtin_amdgcn_readlane(__float_as_int(v), l));
}
__device__ __forceinline__ unsigned cvtpk_bf16(float lo, float hi) {
    unsigned r;
    asm("v_cvt_pk_bf16_f32 %0, %1, %2" : "=v"(r) : "v"(lo), "v"(hi));
    return r;
}
__device__ __forceinline__ float fast_exp2(float x) {
    float r;
    asm("v_exp_f32 %0, %1" : "=v"(r) : "v"(x));
    return r;
}
// A/B fragment k-index for mfma_f32_16x16x32_bf16, SPLIT-HALF mapping
// (validated round 6, absmax=0): e=0..3 -> k=4*gq+e ; e=4..7 -> k=16+4*gq+(e-4)
__device__ __forceinline__ int krow(int kt, int gq, int e) {
    return 32 * kt + ((e >> 2) << 4) + 4 * gq + (e & 3);
}

// ============================================================================
// Phase 1, ROUND 17 — COLUMN-SPLIT: Z's columns evolve independently
// (C[i][col] = sum_k A[i][k] B[k][col]; A is the same for all columns), so
// each chunk (b,g) is computed by FOUR waves, each owning 16 columns, with
// NO cross-wave communication in the loop. Total instruction count is ~flat
// (d4 build replicated; MFMA/max/cvt split 4-ways) but wave count goes
// 2048 -> 8192: the latency-bound chain (r9-r16: all configs ~52-57us,
// VALUBusy 40-50%) finally gets enough co-resident waves to hide stalls.
// Per-wave live set ~110 regs -> fits 128-reg budget at 4 waves/EU.
// Each wave keeps its own lazy lag-2 pow2 rescale (kc/ktot); per-column-
// group scales are combined EXACTLY in apply via pow2 weights.
// ============================================================================
template<int GG>
__global__ __launch_bounds__(256, 4)
void crf_col4(const float* __restrict__ features,
              const float* __restrict__ mask,
              const float* __restrict__ transitions,
              unsigned short* __restrict__ Zout,
              int* __restrict__ Kout)
{
    constexpr int CLT = S / GG;                 // 32 steps per chunk
    __shared__ unsigned short relay[T * 68];    // one slab: 4 waves, disjoint cols

    const int wid  = threadIdx.x >> 6;          // column group (0..3)
    const int lane = threadIdx.x & 63;
    const int b  = blockIdx.x / GG;
    const int g  = blockIdx.x % GG;
    const int c  = lane & 15;
    const int gq = lane >> 4;
    const int mycol = 16 * wid + c;             // this wave's column for lane

    // ---- static A = E^T in bf16 fragments (full rows; shared shape) ----
    bf16x8 Ef[4][2];
    #pragma unroll
    for (int rt = 0; rt < 4; ++rt)
      #pragma unroll
      for (int kt = 0; kt < 2; ++kt) {
          unsigned dw[4];
          #pragma unroll
          for (int w = 0; w < 4; ++w) {
              int k0 = krow(kt, gq, 2 * w);
              float x0 = __expf(transitions[k0       * T + (c + 16*rt)]);
              float x1 = __expf(transitions[(k0 + 1) * T + (c + 16*rt)]);
              dw[w] = cvtpk_bf16(x0, x1);
          }
          uint4 q; q.x = dw[0]; q.y = dw[1]; q.z = dw[2]; q.w = dw[3];
          Ef[rt][kt] = __builtin_bit_cast(bf16x8, q);
      }

    // ---- Z columns (this wave's 16): init = identity slice ----
    bf16x8 Bf[2];
    #pragma unroll
    for (int kt = 0; kt < 2; ++kt)
      #pragma unroll
      for (int e = 0; e < 8; ++e)
          Bf[kt][e] = (krow(kt, gq, e) == mycol) ? (short)0x3F80 : (short)0;

    const float* fb = features + (size_t)b * S * T;
    const float* mb = mask + (size_t)b * S;
    const int t0 = g * CLT + 1;
    const int t1 = (g == GG - 1) ? S : (t0 + CLT);

    const f32x4 zero4 = {0.f, 0.f, 0.f, 0.f};

    int ktot = 0;
    float zloc = 1.0f, mxr = 1.0f;

    // emission/mask prefetch depth 1 (rows 16*rt + 4*gq .. +3, coalesced)
    f32x4 emP[4];
    #pragma unroll
    for (int rt = 0; rt < 4; ++rt)
        emP[rt] = *(const f32x4*)(fb + t0 * T + 16*rt + 4*gq);
    float mP = mb[t0];

    for (int w = 0; w < CLT / 4; ++w) {
        #pragma unroll
        for (int j = 0; j < 4; ++j) {
            const int t = t0 + 4 * w + j;
            const bool act = (t < t1);

            f32x4 emc[4];
            #pragma unroll
            for (int rt = 0; rt < 4; ++rt) emc[rt] = emP[rt];
            float mc = mP;
            {   // prefetch t+1
                int tn = min(t + 1, S - 1);
                #pragma unroll
                for (int rt = 0; rt < 4; ++rt)
                    emP[rt] = *(const f32x4*)(fb + tn * T + 16*rt + 4*gq);
                mP = mb[tn];
            }

            int kc = 0;
            if (j == 0) {   // consume reduce launched in window w-1 (lag-2)
                kc = ((__float_as_int(mxr) >> 23) & 0xFF) - 127;
                kc = kc < -30 ? -30 : (kc > 60 ? 60 : kc);
            }

            if (act && mc != 0.0f) {
                if (j == 0) ktot += kc;
                const float kcf = (j == 0) ? (float)kc : 0.0f;

                // d4[tr][r] = exp(em[row]) * 2^-kc (off the MFMA chain)
                f32x4 d4[4];
                #pragma unroll
                for (int rt = 0; rt < 4; ++rt)
                    #pragma unroll
                    for (int r = 0; r < 4; ++r)
                        d4[rt][r] = fast_exp2(fmaf(emc[rt][r], 1.44269504f, -kcf));

                // this wave's 16 columns: 8 MFMAs -> scale -> max -> repack
                f32x4 Ct[4];
                #pragma unroll
                for (int tr = 0; tr < 4; ++tr) {
                    f32x4 z = __builtin_amdgcn_mfma_f32_16x16x32_bf16(Ef[tr][0], Bf[0], zero4, 0, 0, 0);
                    z = __builtin_amdgcn_mfma_f32_16x16x32_bf16(Ef[tr][1], Bf[1], z, 0, 0, 0);
                    Ct[tr] = z * d4[tr];
                }
                #pragma unroll
                for (int tr = 0; tr < 4; ++tr)
                    zloc = fmaxf(zloc, fmaxf(fmaxf(Ct[tr][0], Ct[tr][1]),
                                             fmaxf(Ct[tr][2], Ct[tr][3])));
                uint4 q0, q1;
                q0.x = cvtpk_bf16(Ct[0][0], Ct[0][1]);
                q0.y = cvtpk_bf16(Ct[0][2], Ct[0][3]);
                q0.z = cvtpk_bf16(Ct[1][0], Ct[1][1]);
                q0.w = cvtpk_bf16(Ct[1][2], Ct[1][3]);
                q1.x = cvtpk_bf16(Ct[2][0], Ct[2][1]);
                q1.y = cvtpk_bf16(Ct[2][2], Ct[2][3]);
                q1.z = cvtpk_bf16(Ct[3][0], Ct[3][1]);
                q1.w = cvtpk_bf16(Ct[3][2], Ct[3][3]);
                Bf[0] = __builtin_bit_cast(bf16x8, q0);
                Bf[1] = __builtin_bit_cast(bf16x8, q1);
            }

            if (j == 2) {   // per-wave cross-lane reduce (lag-2 consume)
                float mr = zloc;
                #pragma unroll
                for (int o = 32; o > 0; o >>= 1)
                    mr = fmaxf(mr, __shfl_xor(mr, o));
                mxr = mr; zloc = 1.0f;
            }
        }
    }

    // ---- assemble Z in the shared slab (disjoint cols), store row-major ----
    {
        uint4 q = __builtin_bit_cast(uint4, Bf[0]);
        uint4 p = __builtin_bit_cast(uint4, Bf[1]);
        uint2 wa; wa.x = q.x; wa.y = q.y;       // rows  4gq+0..3
        uint2 wb; wb.x = q.z; wb.y = q.w;       // rows 16+4gq+0..3
        uint2 wc; wc.x = p.x; wc.y = p.y;       // rows 32+4gq+0..3
        uint2 wd; wd.x = p.z; wd.y = p.w;       // rows 48+4gq+0..3
        *(uint2*)&relay[mycol * 68 +      4*gq] = wa;
        *(uint2*)&relay[mycol * 68 + 16 + 4*gq] = wb;
        *(uint2*)&relay[mycol * 68 + 32 + 4*gq] = wc;
        *(uint2*)&relay[mycol * 68 + 48 + 4*gq] = wd;
    }
    if (lane == 0) Kout[((size_t)b * GG + g) * 4 + wid] = ktot;
    __syncthreads();

    if (wid == 0) {   // wave 0 stores full Z row-major (lane = row)
        unsigned short* zo = Zout + ((size_t)(b * GG + g)) * 64 * 64;
        #pragma unroll
        for (int q8 = 0; q8 < 8; ++q8) {
            unsigned dw[4];
            #pragma unroll
            for (int d = 0; d < 4; ++d) {
                unsigned lo = relay[(8*q8 + 2*d    ) * 68 + lane];
                unsigned hi = relay[(8*q8 + 2*d + 1) * 68 + lane];
                dw[d] = lo | (hi << 16);
            }
            uint4 wv; wv.x = dw[0]; wv.y = dw[1]; wv.z = dw[2]; wv.w = dw[3];
            *(uint4*)(zo + (size_t)lane * 64 + 8*q8) = wv;
        }
    }
}

// ============================================================================
// Phase 2: one wave per batch, v <- Z_g v. Per-column-group K scales are
// combined exactly: acc = sum_G s_G * 2^(K_G - Kmax); esum += Kmax + e.
// Normalizer = exact pow2 from lane-1's exponent (r13-validated).
// ============================================================================
template<int GG>
__global__ __launch_bounds__(64, 1)
void crf_apply(const float* __restrict__ features,
               const int*   __restrict__ labels,
               const float* __restrict__ mask,
               const float* __restrict__ transitions,
               const unsigned short* __restrict__ Zmat,
               const int*   __restrict__ Kscale,
               float*       __restrict__ res)
{
    __shared__ float trans_lds[T * T];
    __shared__ float bcast[2][T];
    const int lane = threadIdx.x;
    const int b = blockIdx.x;

    for (int i = 0; i < T; ++i)
        trans_lds[i * T + lane] = transitions[i * T + lane];
    __syncthreads();

    const float* fb = features + (size_t)b * S * T;
    const int*   lb = labels + (size_t)b * S;
    const float* mb = mask + (size_t)b * S;

    // ---- gold score (lane i handles t = 64*ch + i) ----
    float gold = 0.f;
    #pragma unroll
    for (int ch = 0; ch < S / T; ++ch) {
        int tt = ch * T + lane;
        int tm1 = tt > 0 ? tt - 1 : 0;
        int la = lb[tt], lp = lb[tm1];
        float mt = mb[tt], mp = mb[tm1];
        float em_g = fb[(size_t)tt * T + la];
        float tr_g = trans_lds[lp * T + la];
        gold += em_g * mt + ((tt > 0) ? tr_g * (mp * mt) : 0.f);
    }

    // ---- v init from alpha_0 = em_0, normalized by wave max ----
    float a0 = fb[lane];
    float A0 = a0;
    #pragma unroll
    for (int o = 32; o > 0; o >>= 1) A0 = fmaxf(A0, __shfl_xor(A0, o));
    float v = __expf(a0 - A0);

    int esum = 0;

    const unsigned short* zb = Zmat + ((size_t)b * GG) * 64 * 64 + (size_t)lane * 64;
    uint4 cur[8], nxt[8];
    #pragma unroll
    for (int i = 0; i < 8; ++i) cur[i] = ((const uint4*)zb)[i];

    for (int g = 0; g < GG; ++g) {
        if (g + 1 < GG) {
            const uint4* zn = (const uint4*)(zb + (size_t)(g + 1) * 64 * 64);
            #pragma unroll
            for (int i = 0; i < 8; ++i) nxt[i] = zn[i];
        }
        int4 k4 = *(const int4*)(Kscale + ((size_t)b * GG + g) * 4);

        const int buf = g & 1;
        bcast[buf][lane] = v;
        asm volatile("s_waitcnt lgkmcnt(0)" ::: "memory");
        f32x4 vb[16];
        #pragma unroll
        for (int q = 0; q < 16; ++q) vb[q] = ((const f32x4*)bcast[buf])[q];

        // per-column-group partial sums (group = i>>1; k = 8i..8i+7)
        float s0 = 0.f, s1 = 0.f, s2 = 0.f, s3 = 0.f;
        #pragma unroll
        for (int i = 0; i < 8; ++i) {
            unsigned zz[4] = {cur[i].x, cur[i].y, cur[i].z, cur[i].w};
            float part = 0.f;
            #pragma unroll
            for (int d = 0; d < 4; ++d) {
                int k = i * 8 + d * 2;
                float f0 = __int_as_float(zz[d] << 16);
                float f1 = __int_as_float(zz[d] & 0xFFFF0000u);
                part = fmaf(f0, vb[k >> 2][k & 3], part);
                part = fmaf(f1, vb[(k + 1) >> 2][(k + 1) & 3], part);
            }
            if (i < 2)      s0 += part;
            else if (i < 4) s1 += part;
            else if (i < 6) s2 += part;
            else            s3 += part;
        }
        // exact pow2 recombination of per-group scales
        int kmax = max(max(k4.x, k4.y), max(k4.z, k4.w));
        int d0 = max(k4.x - kmax, -127), d1 = max(k4.y - kmax, -127);
        int d2 = max(k4.z - kmax, -127), d3 = max(k4.w - kmax, -127);
        float acc = s0 * __int_as_float((unsigned)(127 + d0) << 23)
                  + s1 * __int_as_float((unsigned)(127 + d1) << 23)
                  + s2 * __int_as_float((unsigned)(127 + d2) << 23)
                  + s3 * __int_as_float((unsigned)(127 + d3) << 23);

        // exact pow2 normalizer from lane 1's exponent (lane 0 is PAD -> 0)
        float a1 = fmaxf(rdlane(acc, 1), 1e-30f);
        int e = ((__float_as_int(a1) >> 23) & 0xFF) - 127;
        v = acc * __int_as_float((unsigned)(127 - e) << 23);
        esum += e + kmax;

        #pragma unroll
        for (int i = 0; i < 8; ++i) cur[i] = nxt[i];
    }

    float sum = v;
    #pragma unroll
    for (int o = 32; o > 0; o >>= 1) sum += __shfl_xor(sum, o);
    float logZ = __logf(fmaxf(sum, 1e-30f)) + A0 + (float)esum * 0.69314718056f;

    #pragma unroll
    for (int o = 32; o > 0; o >>= 1) gold += __shfl_xor(gold, o);

    if (lane == 0) res[b] = logZ - gold;
}

// ============================================================================
// Fallback: validated round-3 sequential kernel (used if ws too small)
// ============================================================================
__global__ __launch_bounds__(64, 1)
void crf_fwd_seq(const float* __restrict__ features,
                 const int*   __restrict__ labels,
                 const float* __restrict__ mask,
                 const float* __restrict__ transitions,
                 float*       __restrict__ ws)
{
    __shared__ float trans_lds[T * T];
    __shared__ __align__(16) _Float16 ea_lds[2][T];

    const int lane = threadIdx.x;
    const int b    = blockIdx.x;

    for (int i = 0; i < T; ++i)
        trans_lds[i * T + lane] = transitions[i * T + lane];
    __syncthreads();

    h2 etr[T / 2];
    #pragma unroll
    for (int k = 0; k < T / 2; ++k) {
        etr[k].x = (_Float16)__expf(trans_lds[(2 * k + 0) * T + lane]);
        etr[k].y = (_Float16)__expf(trans_lds[(2 * k + 1) * T + lane]);
    }

    const float* fb = features + (size_t)b * S * T;
    const float* mb = mask + (size_t)b * S;
    const int*   lb = labels + (size_t)b * S;

    float alpha = fb[lane];
    float gold_part = 0.f;
    float M = 0.f;

    float em_n1 = fb[1 * T + lane];
    float em_n2 = fb[2 * T + lane];
    float em_n3 = fb[3 * T + lane];

    int   lab_c = lb[lane];
    int   lab_p = lb[lane > 0 ? lane - 1 : 0];
    float m_c   = mb[lane];
    float m_p   = mb[lane > 0 ? lane - 1 : 0];

    for (int ch = 0; ch < S / T; ++ch) {
        const int base = ch * T;
        const int tt   = base + lane;

        const int   glab  = lab_c;
        const int   glabp = lab_p;
        const float gmc   = m_c;
        const float gmp   = m_p;
        const float mreg  = m_c;

        float em_g = fb[(size_t)tt * T + glab];
        float tr_g = trans_lds[glabp * T + glab];

        {
            int tn  = tt + T;  if (tn > S - 1) tn = S - 1;
            int tnp = tn - 1;  if (tnp < 0) tnp = 0;
            lab_c = lb[tn]; lab_p = lb[tnp];
            m_c   = mb[tn]; m_p   = mb[tnp];
        }

        const int i0 = (ch == 0) ? 1 : 0;
        #pragma unroll 4
        for (int i = i0; i < T; ++i) {
            const int t = base + i;
            float em = em_n1;
            em_n1 = em_n2; em_n2 = em_n3;
            int tn = t + 3; if (tn > S - 1) tn = S - 1;
            em_n3 = fb[tn * T + lane];

            float ea = __expf(alpha - M);
            ea_lds[t & 1][lane] = (_Float16)ea;
            asm volatile("s_waitcnt lgkmcnt(0)" ::: "memory");

            const uint4* ep = (const uint4*)&ea_lds[t & 1][0];
            float a0 = 0.f, a1 = 0.f, a2 = 0.f, a3 = 0.f;
            #pragma unroll
            for (int q = 0; q < 8; ++q) {
                uint4 r = ep[q];
                a0 = __builtin_amdgcn_fdot2(__builtin_bit_cast(h2, r.x), etr[4 * q + 0], a0, false);
                a1 = __builtin_amdgcn_fdot2(__builtin_bit_cast(h2, r.y), etr[4 * q + 1], a1, false);
                a2 = __builtin_amdgcn_fdot2(__builtin_bit_cast(h2, r.z), etr[4 * q + 2], a2, false);
                a3 = __builtin_amdgcn_fdot2(__builtin_bit_cast(h2, r.w), etr[4 * q + 3], a3, false);
            }
            float s = (a0 + a1) + (a2 + a3);

            float m_t = rdlane(mreg, i);
            float s1  = rdlane(s, 1);
            float em1 = rdlane(em, 1);
            float Mn  = M + __logf(s1) + em1;

            float val = M + __logf(s) + em;
            val = fmaxf(val, -1e30f);
            alpha = val * m_t + alpha * (1.f - m_t);
            M     = (m_t > 0.5f) ? Mn : M;
        }

        float valid = (tt > 0) ? 1.f : 0.f;
        gold_part += em_g * gmc + tr_g * (gmp * gmc) * valid;
    }

    float M2 = alpha;
    #pragma unroll
    for (int o = 32; o > 0; o >>= 1) M2 = fmaxf(M2, __shfl_xor(M2, o));
    float e2 = __expf(alpha - M2);
    #pragma unroll
    for (int o = 32; o > 0; o >>= 1) e2 += __shfl_xor(e2, o);
    float logZ = M2 + __logf(e2);

    #pragma unroll
    for (int o = 32; o > 0; o >>= 1) gold_part += __shfl_xor(gold_part, o);

    if (lane == 0) ws[b] = logZ - gold_part;
}

// Deterministic final mean over B=128 per-batch results.
__global__ __launch_bounds__(128)
void crf_reduce(const float* __restrict__ ws, float* __restrict__ out)
{
    const int tid = threadIdx.x;
    float v = ws[tid];
    #pragma unroll
    for (int o = 32; o > 0; o >>= 1) v += __shfl_xor(v, o);

    __shared__ float partial[2];
    if ((tid & 63) == 0) partial[tid >> 6] = v;
    __syncthreads();
    if (tid == 0) out[0] = (partial[0] + partial[1]) * (1.0f / (float)B);
}

extern "C" void kernel_launch(void* const* d_in, const int* in_sizes, int n_in,
                              void* d_out, int out_size, void* d_ws, size_t ws_size,
                              hipStream_t stream)
{
    const float* features    = (const float*)d_in[0]; // (B,S,T) f32
    const int*   labels      = (const int*)  d_in[1]; // (B,S) int
    const float* mask        = (const float*)d_in[2]; // (B,S) f32
    const float* transitions = (const float*)d_in[3]; // (T,T) f32
    float* out = (float*)d_out;

    constexpr int GG = 16;
    const size_t zbytes = (size_t)B * GG * 64 * 64 * sizeof(unsigned short); // 16 MB
    const size_t kbytes = (size_t)B * GG * 4 * sizeof(int);
    const size_t need   = zbytes + kbytes + (size_t)B * sizeof(float);

    if (ws_size >= need) {
        unsigned short* Zmat = (unsigned short*)d_ws;
        int*   Ks  = (int*)((char*)d_ws + zbytes);
        float* res = (float*)((char*)d_ws + zbytes + kbytes);
        crf_col4<GG><<<dim3(B * GG), dim3(256), 0, stream>>>(features, mask, transitions, Zmat, Ks);
        crf_apply<GG><<<dim3(B), dim3(64), 0, stream>>>(features, labels, mask, transitions, Zmat, Ks, res);
        crf_reduce<<<dim3(1), dim3(128), 0, stream>>>(res, out);
    } else {
        float* res = (float*)d_ws;
        crf_fwd_seq<<<dim3(B), dim3(64), 0, stream>>>(features, labels, mask, transitions, res);
        crf_reduce<<<dim3(1), dim3(128), 0, stream>>>(res, out);
    }
}

// Round 18
// 58.181 us; speedup vs baseline: 1.3442x; 1.3442x over previous
//
#include <hip/hip_runtime.h>

#define B 128
#define S 512
#define T 64
#define G 16

typedef short bf16x8 __attribute__((ext_vector_type(8)));
typedef float f32x4 __attribute__((ext_vector_type(4)));
typedef float f32x2 __attribute__((ext_vector_type(2)));
typedef _Float16 h2 __attribute__((ext_vector_type(2)));

__device__ __forceinline__ float rdlane(float v, int l) {
    return __int_as_float(__builtin_amdgcn_readlane(__float_as_int(v), l));
}
__device__ __forceinline__ unsigned cvtpk_bf16(float lo, float hi) {
    unsigned r;
    asm("v_cvt_pk_bf16_f32 %0, %1, %2" : "=v"(r) : "v"(lo), "v"(hi));
    return r;
}
__device__ __forceinline__ float fast_exp2(float x) {
    float r;
    asm("v_exp_f32 %0, %1" : "=v"(r) : "v"(x));
    return r;
}
__device__ __forceinline__ float max3f(float a, float b, float c) {
    float r;
    asm("v_max3_f32 %0, %1, %2, %3" : "=v"(r) : "v"(a), "v"(b), "v"(c));
    return r;
}
// A/B fragment k-index for mfma_f32_16x16x32_bf16, SPLIT-HALF mapping
// (validated round 6, absmax=0): e=0..3 -> k=4*gq+e ; e=4..7 -> k=16+4*gq+(e-4)
__device__ __forceinline__ int krow(int kt, int gq, int e) {
    return 32 * kt + ((e >> 2) << 4) + 4 * gq + (e & 3);
}

// ============================================================================
// Phase 1 (r13-exact structure — best measured config, 53.6us chunk / 62.2
// total — plus max3 tree): one wave per (batch, chunk); Z product in bf16;
// LAZY pow2 rescale (local max per step via v_max3, cross-lane reduce every
// 4th step, lag-2 consume). Per-step chain: A'-build (f32 pk_mul + cvt_pk)
// -> MFMA -> cvt_pk -> next. E^T in f32 pre-paired; d folded per-row A-side.
// launch_bounds(64,2): 256-VGPR budget, no spill (r13: FETCH 9.2MB clean).
// ============================================================================
template<int GG>
__global__ __launch_bounds__(64, 2)
void crf_chunk_bf(const float* __restrict__ features,
                  const float* __restrict__ mask,
                  const float* __restrict__ transitions,
                  unsigned short* __restrict__ Zout,
                  int* __restrict__ Kout)
{
    constexpr int CLT = S / GG;                // 32
    __shared__ unsigned short relay[T * 68];   // used ONCE at end

    const int lane = threadIdx.x;
    const int b  = blockIdx.x / GG;
    const int g  = blockIdx.x % GG;
    const int c  = lane & 15;
    const int gq = lane >> 4;

    // ---- static E^T in f32, pre-paired for cvt_pk: e32[rt][kt][w] =
    //      { exp(W[k0][i]), exp(W[k0+1][i]) }, k0 = krow(kt,gq,2w), i=c+16rt
    f32x2 e32[4][2][4];                        // 64 VGPRs
    #pragma unroll
    for (int rt = 0; rt < 4; ++rt)
      #pragma unroll
      for (int kt = 0; kt < 2; ++kt)
        #pragma unroll
        for (int w = 0; w < 4; ++w) {
            int k0 = krow(kt, gq, 2 * w);
            e32[rt][kt][w][0] = __expf(transitions[k0       * T + (c + 16*rt)]);
            e32[rt][kt][w][1] = __expf(transitions[(k0 + 1) * T + (c + 16*rt)]);
        }

    // ---- Z init = identity, in B-fragment layout (bf16 1.0 = 0x3F80) ----
    bf16x8 Bf[2][4];
    #pragma unroll
    for (int kt = 0; kt < 2; ++kt)
      #pragma unroll
      for (int ct = 0; ct < 4; ++ct)
        #pragma unroll
        for (int e = 0; e < 8; ++e)
            Bf[kt][ct][e] = (krow(kt, gq, e) == 16*ct + c) ? (short)0x3F80
                                                           : (short)0;

    const float* fb   = features + (size_t)b * S * T;
    const float* colp = fb + c;
    const float* mb   = mask + (size_t)b * S;
    const int t0 = g * CLT + 1;
    const int t1 = (g == GG - 1) ? S : (t0 + CLT);

    const f32x4 zero4 = {0.f, 0.f, 0.f, 0.f};  // shared C-in for first MFMA

    int ktot = 0;
    float zloc = 1.0f;     // running local max since last measure
    float mxr  = 1.0f;     // reduced max from last measure (lag-2)

    // emission/mask prefetch, depth 2
    float em1[4], em2[4];
    #pragma unroll
    for (int rt = 0; rt < 4; ++rt) {
        em1[rt] = colp[t0 * T + 16*rt];
        em2[rt] = colp[min(t0 + 1, S - 1) * T + 16*rt];
    }
    float m1 = mb[t0], m2 = mb[min(t0 + 1, S - 1)];

    for (int w = 0; w < CLT / 4; ++w) {
        #pragma unroll
        for (int j = 0; j < 4; ++j) {
            const int i = 4 * w + j;
            const int t = t0 + i;
            const bool act = (t < t1);

            float emc[4];
            #pragma unroll
            for (int rt = 0; rt < 4; ++rt) emc[rt] = em1[rt];
            float mc = m1;
            {   // rotate + prefetch t+2
                int t2 = min(t + 2, S - 1);
                #pragma unroll
                for (int rt = 0; rt < 4; ++rt) {
                    em1[rt] = em2[rt];
                    em2[rt] = colp[t2 * T + 16*rt];
                }
                m1 = m2; m2 = mb[t2];
            }

            int kc = 0;
            if (j == 0) {   // finish measure from window w-1
                kc = ((__float_as_int(mxr) >> 23) & 0xFF) - 127;
                kc = kc < -30 ? -30 : (kc > 60 ? 60 : kc);
            }

            if (act && mc != 0.0f) {
                const float kcf = (j == 0) ? (float)kc : 0.0f;
                // A' = (d .* E^T) in bf16; d = exp2(em*log2e - kc)
                bf16x8 Ap[4][2];
                #pragma unroll
                for (int rt = 0; rt < 4; ++rt) {
                    float d = fast_exp2(fmaf(emc[rt], 1.44269504f, -kcf));
                    f32x2 dd; dd[0] = d; dd[1] = d;
                    #pragma unroll
                    for (int kt = 0; kt < 2; ++kt) {
                        unsigned dw[4];
                        #pragma unroll
                        for (int q = 0; q < 4; ++q) {
                            f32x2 p = e32[rt][kt][q] * dd;   // v_pk_mul_f32
                            dw[q] = cvtpk_bf16(p[0], p[1]);
                        }
                        uint4 qq; qq.x = dw[0]; qq.y = dw[1]; qq.z = dw[2]; qq.w = dw[3];
                        Ap[rt][kt] = __builtin_bit_cast(bf16x8, qq);
                    }
                }
                if (j == 0) ktot += kc;

                // per output-column: 8 MFMAs -> local-max (max3) -> repack
                #pragma unroll
                for (int ct = 0; ct < 4; ++ct) {
                    f32x4 Ct[4];
                    #pragma unroll
                    for (int tr = 0; tr < 4; ++tr) {
                        f32x4 z = __builtin_amdgcn_mfma_f32_16x16x32_bf16(Ap[tr][0], Bf[0][ct], zero4, 0, 0, 0);
                        z = __builtin_amdgcn_mfma_f32_16x16x32_bf16(Ap[tr][1], Bf[1][ct], z, 0, 0, 0);
                        Ct[tr] = z;
                    }
                    #pragma unroll
                    for (int tr = 0; tr < 4; ++tr) {
                        float m012 = max3f(Ct[tr][0], Ct[tr][1], Ct[tr][2]);
                        zloc = max3f(zloc, m012, Ct[tr][3]);
                    }
                    uint4 q0, q1;
                    q0.x = cvtpk_bf16(Ct[0][0], Ct[0][1]);
                    q0.y = cvtpk_bf16(Ct[0][2], Ct[0][3]);
                    q0.z = cvtpk_bf16(Ct[1][0], Ct[1][1]);
                    q0.w = cvtpk_bf16(Ct[1][2], Ct[1][3]);
                    q1.x = cvtpk_bf16(Ct[2][0], Ct[2][1]);
                    q1.y = cvtpk_bf16(Ct[2][2], Ct[2][3]);
                    q1.z = cvtpk_bf16(Ct[3][0], Ct[3][1]);
                    q1.w = cvtpk_bf16(Ct[3][2], Ct[3][3]);
                    Bf[0][ct] = __builtin_bit_cast(bf16x8, q0);
                    Bf[1][ct] = __builtin_bit_cast(bf16x8, q1);
                }
            }

            if (j == 2) {   // launch cross-lane reduce (consumed next window)
                float mr = zloc;
                #pragma unroll
                for (int o = 32; o > 0; o >>= 1)
                    mr = fmaxf(mr, __shfl_xor(mr, o));
                mxr  = mr;
                zloc = 1.0f;
            }
        }
    }

    // ---- ONE-TIME relayout to row-major bf16 Zout via LDS ----
    #pragma unroll
    for (int kt = 0; kt < 2; ++kt)
      #pragma unroll
      for (int ct = 0; ct < 4; ++ct) {
          uint4 q = __builtin_bit_cast(uint4, Bf[kt][ct]);
          int col = 16*ct + c;
          uint2 wa; wa.x = q.x; wa.y = q.y;     // rows 32kt+4gq+0..3
          uint2 wb; wb.x = q.z; wb.y = q.w;     // rows 32kt+16+4gq+0..3
          *(uint2*)&relay[col * 68 + 32*kt      + 4*gq] = wa;
          *(uint2*)&relay[col * 68 + 32*kt + 16 + 4*gq] = wb;
      }
    asm volatile("s_waitcnt lgkmcnt(0)" ::: "memory");

    unsigned short* zo = Zout + ((size_t)(b * GG + g)) * 64 * 64;
    #pragma unroll
    for (int q8 = 0; q8 < 8; ++q8) {
        unsigned dw[4];
        #pragma unroll
        for (int d = 0; d < 4; ++d) {
            unsigned lo = relay[(8*q8 + 2*d    ) * 68 + lane];
            unsigned hi = relay[(8*q8 + 2*d + 1) * 68 + lane];
            dw[d] = lo | (hi << 16);
        }
        uint4 wv; wv.x = dw[0]; wv.y = dw[1]; wv.z = dw[2]; wv.w = dw[3];
        *(uint4*)(zo + (size_t)lane * 64 + 8*q8) = wv;
    }
    if (lane == 0) Kout[b * GG + g] = ktot;
}

// ============================================================================
// Phase 2 (r13-exact): one wave per batch. v <- Z_g v sequentially;
// normalizer = exact pow2 from lane-1's exponent; esum folded at the end.
// ============================================================================
template<int GG>
__global__ __launch_bounds__(64, 1)
void crf_apply(const float* __restrict__ features,
               const int*   __restrict__ labels,
               const float* __restrict__ mask,
               const float* __restrict__ transitions,
               const unsigned short* __restrict__ Zmat,
               const int*   __restrict__ Kscale,
               float*       __restrict__ res)
{
    __shared__ float trans_lds[T * T];
    __shared__ float bcast[2][T];
    const int lane = threadIdx.x;
    const int b = blockIdx.x;

    for (int i = 0; i < T; ++i)
        trans_lds[i * T + lane] = transitions[i * T + lane];
    __syncthreads();

    const float* fb = features + (size_t)b * S * T;
    const int*   lb = labels + (size_t)b * S;
    const float* mb = mask + (size_t)b * S;

    // ---- gold score (lane i handles t = 64*ch + i) ----
    float gold = 0.f;
    #pragma unroll
    for (int ch = 0; ch < S / T; ++ch) {
        int tt = ch * T + lane;
        int tm1 = tt > 0 ? tt - 1 : 0;
        int la = lb[tt], lp = lb[tm1];
        float mt = mb[tt], mp = mb[tm1];
        float em_g = fb[(size_t)tt * T + la];
        float tr_g = trans_lds[lp * T + la];
        gold += em_g * mt + ((tt > 0) ? tr_g * (mp * mt) : 0.f);
    }

    // ---- v init from alpha_0 = em_0, normalized by wave max (one-time) ----
    float a0 = fb[lane];
    float A0 = a0;
    #pragma unroll
    for (int o = 32; o > 0; o >>= 1) A0 = fmaxf(A0, __shfl_xor(A0, o));
    float v = __expf(a0 - A0);

    int esum = 0;

    // double-buffered Z-row loads (lane j holds row j)
    const unsigned short* zb = Zmat + ((size_t)b * GG) * 64 * 64 + (size_t)lane * 64;
    uint4 cur[8], nxt[8];
    #pragma unroll
    for (int i = 0; i < 8; ++i) cur[i] = ((const uint4*)zb)[i];

    for (int g = 0; g < GG; ++g) {
        if (g + 1 < GG) {
            const uint4* zn = (const uint4*)(zb + (size_t)(g + 1) * 64 * 64);
            #pragma unroll
            for (int i = 0; i < 8; ++i) nxt[i] = zn[i];
        }
        const int buf = g & 1;
        bcast[buf][lane] = v;
        asm volatile("s_waitcnt lgkmcnt(0)" ::: "memory");
        f32x4 vb[16];
        #pragma unroll
        for (int q = 0; q < 16; ++q) vb[q] = ((const f32x4*)bcast[buf])[q];

        float ac0 = 0.f, ac1 = 0.f, ac2 = 0.f, ac3 = 0.f;
        #pragma unroll
        for (int i = 0; i < 8; ++i) {
            unsigned zz[4] = {cur[i].x, cur[i].y, cur[i].z, cur[i].w};
            #pragma unroll
            for (int d = 0; d < 4; ++d) {
                int k = i * 8 + d * 2;
                float f0 = __int_as_float(zz[d] << 16);
                float f1 = __int_as_float(zz[d] & 0xFFFF0000u);
                if ((d & 1) == 0) { ac0 = fmaf(f0, vb[k >> 2][k & 3], ac0);
                                    ac1 = fmaf(f1, vb[(k+1) >> 2][(k+1) & 3], ac1); }
                else             { ac2 = fmaf(f0, vb[k >> 2][k & 3], ac2);
                                    ac3 = fmaf(f1, vb[(k+1) >> 2][(k+1) & 3], ac3); }
            }
        }
        float acc = (ac0 + ac1) + (ac2 + ac3);

        // exact pow2 normalizer from lane 1's exponent (lane 0 is PAD -> 0)
        float a1 = fmaxf(rdlane(acc, 1), 1e-30f);
        int e = ((__float_as_int(a1) >> 23) & 0xFF) - 127;
        v = acc * __int_as_float((unsigned)(127 - e) << 23);
        esum += e + Kscale[b * GG + g];

        #pragma unroll
        for (int i = 0; i < 8; ++i) cur[i] = nxt[i];
    }

    float sum = v;
    #pragma unroll
    for (int o = 32; o > 0; o >>= 1) sum += __shfl_xor(sum, o);
    float logZ = __logf(fmaxf(sum, 1e-30f)) + A0 + (float)esum * 0.69314718056f;

    #pragma unroll
    for (int o = 32; o > 0; o >>= 1) gold += __shfl_xor(gold, o);

    if (lane == 0) res[b] = logZ - gold;
}

// ============================================================================
// Fallback: validated round-3 sequential kernel (used if ws too small)
// ============================================================================
__global__ __launch_bounds__(64, 1)
void crf_fwd_seq(const float* __restrict__ features,
                 const int*   __restrict__ labels,
                 const float* __restrict__ mask,
                 const float* __restrict__ transitions,
                 float*       __restrict__ ws)
{
    __shared__ float trans_lds[T * T];
    __shared__ __align__(16) _Float16 ea_lds[2][T];

    const int lane = threadIdx.x;
    const int b    = blockIdx.x;

    for (int i = 0; i < T; ++i)
        trans_lds[i * T + lane] = transitions[i * T + lane];
    __syncthreads();

    h2 etr[T / 2];
    #pragma unroll
    for (int k = 0; k < T / 2; ++k) {
        etr[k].x = (_Float16)__expf(trans_lds[(2 * k + 0) * T + lane]);
        etr[k].y = (_Float16)__expf(trans_lds[(2 * k + 1) * T + lane]);
    }

    const float* fb = features + (size_t)b * S * T;
    const float* mb = mask + (size_t)b * S;
    const int*   lb = labels + (size_t)b * S;

    float alpha = fb[lane];
    float gold_part = 0.f;
    float M = 0.f;

    float em_n1 = fb[1 * T + lane];
    float em_n2 = fb[2 * T + lane];
    float em_n3 = fb[3 * T + lane];

    int   lab_c = lb[lane];
    int   lab_p = lb[lane > 0 ? lane - 1 : 0];
    float m_c   = mb[lane];
    float m_p   = mb[lane > 0 ? lane - 1 : 0];

    for (int ch = 0; ch < S / T; ++ch) {
        const int base = ch * T;
        const int tt   = base + lane;

        const int   glab  = lab_c;
        const int   glabp = lab_p;
        const float gmc   = m_c;
        const float gmp   = m_p;
        const float mreg  = m_c;

        float em_g = fb[(size_t)tt * T + glab];
        float tr_g = trans_lds[glabp * T + glab];

        {
            int tn  = tt + T;  if (tn > S - 1) tn = S - 1;
            int tnp = tn - 1;  if (tnp < 0) tnp = 0;
            lab_c = lb[tn]; lab_p = lb[tnp];
            m_c   = mb[tn]; m_p   = mb[tnp];
        }

        const int i0 = (ch == 0) ? 1 : 0;
        #pragma unroll 4
        for (int i = i0; i < T; ++i) {
            const int t = base + i;
            float em = em_n1;
            em_n1 = em_n2; em_n2 = em_n3;
            int tn = t + 3; if (tn > S - 1) tn = S - 1;
            em_n3 = fb[tn * T + lane];

            float ea = __expf(alpha - M);
            ea_lds[t & 1][lane] = (_Float16)ea;
            asm volatile("s_waitcnt lgkmcnt(0)" ::: "memory");

            const uint4* ep = (const uint4*)&ea_lds[t & 1][0];
            float a0 = 0.f, a1 = 0.f, a2 = 0.f, a3 = 0.f;
            #pragma unroll
            for (int q = 0; q < 8; ++q) {
                uint4 r = ep[q];
                a0 = __builtin_amdgcn_fdot2(__builtin_bit_cast(h2, r.x), etr[4 * q + 0], a0, false);
                a1 = __builtin_amdgcn_fdot2(__builtin_bit_cast(h2, r.y), etr[4 * q + 1], a1, false);
                a2 = __builtin_amdgcn_fdot2(__builtin_bit_cast(h2, r.z), etr[4 * q + 2], a2, false);
                a3 = __builtin_amdgcn_fdot2(__builtin_bit_cast(h2, r.w), etr[4 * q + 3], a3, false);
            }
            float s = (a0 + a1) + (a2 + a3);

            float m_t = rdlane(mreg, i);
            float s1  = rdlane(s, 1);
            float em1 = rdlane(em, 1);
            float Mn  = M + __logf(s1) + em1;

            float val = M + __logf(s) + em;
            val = fmaxf(val, -1e30f);
            alpha = val * m_t + alpha * (1.f - m_t);
            M     = (m_t > 0.5f) ? Mn : M;
        }

        float valid = (tt > 0) ? 1.f : 0.f;
        gold_part += em_g * gmc + tr_g * (gmp * gmc) * valid;
    }

    float M2 = alpha;
    #pragma unroll
    for (int o = 32; o > 0; o >>= 1) M2 = fmaxf(M2, __shfl_xor(M2, o));
    float e2 = __expf(alpha - M2);
    #pragma unroll
    for (int o = 32; o > 0; o >>= 1) e2 += __shfl_xor(e2, o);
    float logZ = M2 + __logf(e2);

    #pragma unroll
    for (int o = 32; o > 0; o >>= 1) gold_part += __shfl_xor(gold_part, o);

    if (lane == 0) ws[b] = logZ - gold_part;
}

// Deterministic final mean over B=128 per-batch results.
__global__ __launch_bounds__(128)
void crf_reduce(const float* __restrict__ ws, float* __restrict__ out)
{
    const int tid = threadIdx.x;
    float v = ws[tid];
    #pragma unroll
    for (int o = 32; o > 0; o >>= 1) v += __shfl_xor(v, o);

    __shared__ float partial[2];
    if ((tid & 63) == 0) partial[tid >> 6] = v;
    __syncthreads();
    if (tid == 0) out[0] = (partial[0] + partial[1]) * (1.0f / (float)B);
}

extern "C" void kernel_launch(void* const* d_in, const int* in_sizes, int n_in,
                              void* d_out, int out_size, void* d_ws, size_t ws_size,
                              hipStream_t stream)
{
    const float* features    = (const float*)d_in[0]; // (B,S,T) f32
    const int*   labels      = (const int*)  d_in[1]; // (B,S) int
    const float* mask        = (const float*)d_in[2]; // (B,S) f32
    const float* transitions = (const float*)d_in[3]; // (T,T) f32
    float* out = (float*)d_out;

    const size_t zbytes = (size_t)B * G * 64 * 64 * sizeof(unsigned short); // 16 MB
    const size_t kbytes = (size_t)B * G * sizeof(int);
    const size_t need   = zbytes + kbytes + (size_t)B * sizeof(float);

    if (ws_size >= need) {
        unsigned short* Zmat = (unsigned short*)d_ws;
        int*   Ks  = (int*)((char*)d_ws + zbytes);
        float* res = (float*)((char*)d_ws + zbytes + kbytes);
        crf_chunk_bf<G><<<dim3(B * G), dim3(64), 0, stream>>>(features, mask, transitions, Zmat, Ks);
        crf_apply<G><<<dim3(B), dim3(64), 0, stream>>>(features, labels, mask, transitions, Zmat, Ks, res);
        crf_reduce<<<dim3(1), dim3(128), 0, stream>>>(res, out);
    } else {
        float* res = (float*)d_ws;
        crf_fwd_seq<<<dim3(B), dim3(64), 0, stream>>>(features, labels, mask, transitions, res);
        crf_reduce<<<dim3(1), dim3(128), 0, stream>>>(res, out);
    }
}

// Round 19
// 57.227 us; speedup vs baseline: 1.3666x; 1.0167x over previous
//
#include <hip/hip_runtime.h>

#define B 128
#define S 512
#define T 64
#define G 16

typedef short bf16x8 __attribute__((ext_vector_type(8)));
typedef float f32x4 __attribute__((ext_vector_type(4)));
typedef _Float16 h2 __attribute__((ext_vector_type(2)));

__device__ __forceinline__ float rdlane(float v, int l) {
    return __int_as_float(__builtin_amdgcn_readlane(__float_as_int(v), l));
}
__device__ __forceinline__ unsigned cvtpk_bf16(float lo, float hi) {
    unsigned r;
    asm("v_cvt_pk_bf16_f32 %0, %1, %2" : "=v"(r) : "v"(lo), "v"(hi));
    return r;
}
__device__ __forceinline__ float fast_exp2(float x) {
    float r;
    asm("v_exp_f32 %0, %1" : "=v"(r) : "v"(x));
    return r;
}
// A/B fragment k-index for mfma_f32_16x16x32_bf16, SPLIT-HALF mapping
// (validated round 6, absmax=0): e=0..3 -> k=4*gq+e ; e=4..7 -> k=16+4*gq+(e-4)
__device__ __forceinline__ int krow(int kt, int gq, int e) {
    return 32 * kt + ((e >> 2) << 4) + 4 * gq + (e & 3);
}

// ============================================================================
// Phase 1, ROUND 19 = r18 minus the entire rescale-measurement machinery.
// FIXED 2^-7/step scaling (folded into the d-exponent, zero cost):
//   per-step log2 growth ≈ 7.4 bits and E re-mixes rows every step, so
//   deviations don't accumulate: extreme |log2 Z| ≈ 26 << 127. No max tree,
//   no cross-lane reduce, no kc logic. ktot = 7 * active_steps (exact).
// Diagonal applied C-SIDE (r14/r16-validated): static bf16 E^T fragments
// (16 VGPRs, replaces the 64-reg f32 pair table), Ct *= d4 row scale.
// Per-step issue ~140 vs r18's ~205. launch_bounds(64,2), no spill.
// ============================================================================
template<int GG>
__global__ __launch_bounds__(64, 2)
void crf_chunk_bf(const float* __restrict__ features,
                  const float* __restrict__ mask,
                  const float* __restrict__ transitions,
                  unsigned short* __restrict__ Zout,
                  int* __restrict__ Kout)
{
    constexpr int CLT = S / GG;                // 32
    __shared__ unsigned short relay[T * 68];   // used ONCE at end

    const int lane = threadIdx.x;
    const int b  = blockIdx.x / GG;
    const int g  = blockIdx.x % GG;
    const int c  = lane & 15;
    const int gq = lane >> 4;

    // ---- static A = E^T in bf16 fragments: A[i][k] = exp(W[k][i]) ----
    bf16x8 Ef[4][2];
    #pragma unroll
    for (int rt = 0; rt < 4; ++rt)
      #pragma unroll
      for (int kt = 0; kt < 2; ++kt) {
          unsigned dw[4];
          #pragma unroll
          for (int w = 0; w < 4; ++w) {
              int k0 = krow(kt, gq, 2 * w);     // even e: k(e+1) = k0+1
              float x0 = __expf(transitions[k0       * T + (c + 16*rt)]);
              float x1 = __expf(transitions[(k0 + 1) * T + (c + 16*rt)]);
              dw[w] = cvtpk_bf16(x0, x1);
          }
          uint4 q; q.x = dw[0]; q.y = dw[1]; q.z = dw[2]; q.w = dw[3];
          Ef[rt][kt] = __builtin_bit_cast(bf16x8, q);
      }

    // ---- Z init = identity, in B-fragment layout (bf16 1.0 = 0x3F80) ----
    bf16x8 Bf[2][4];
    #pragma unroll
    for (int kt = 0; kt < 2; ++kt)
      #pragma unroll
      for (int ct = 0; ct < 4; ++ct)
        #pragma unroll
        for (int e = 0; e < 8; ++e)
            Bf[kt][ct][e] = (krow(kt, gq, e) == 16*ct + c) ? (short)0x3F80
                                                           : (short)0;

    const float* fb = features + (size_t)b * S * T;
    const float* mb = mask + (size_t)b * S;
    const int t0 = g * CLT + 1;
    const int t1 = (g == GG - 1) ? S : (t0 + CLT);

    const f32x4 zero4 = {0.f, 0.f, 0.f, 0.f};  // shared C-in for first MFMA

    int ktot = 0;

    // emission/mask prefetch, depth 2; em rows for C-scale: f32x4 at
    // row0 = 16*rt + 4*gq (the C/D rows this lane owns)
    f32x4 emP1[4], emP2[4];
    #pragma unroll
    for (int rt = 0; rt < 4; ++rt) {
        emP1[rt] = *(const f32x4*)(fb + t0 * T + 16*rt + 4*gq);
        emP2[rt] = *(const f32x4*)(fb + min(t0 + 1, S - 1) * T + 16*rt + 4*gq);
    }
    float m1 = mb[t0], m2 = mb[min(t0 + 1, S - 1)];

    for (int t = t0; t < t1; ++t) {
        f32x4 emc[4];
        #pragma unroll
        for (int rt = 0; rt < 4; ++rt) emc[rt] = emP1[rt];
        float mc = m1;
        {   // rotate + prefetch t+2
            int t2 = min(t + 2, S - 1);
            #pragma unroll
            for (int rt = 0; rt < 4; ++rt) {
                emP1[rt] = emP2[rt];
                emP2[rt] = *(const f32x4*)(fb + t2 * T + 16*rt + 4*gq);
            }
            m1 = m2; m2 = mb[t2];
        }

        if (mc != 0.0f) {
            ktot += 7;
            // d4[tr][r] = exp(em[row]) * 2^-7 = exp2(em*log2e - 7)
            f32x4 d4[4];
            #pragma unroll
            for (int rt = 0; rt < 4; ++rt)
                #pragma unroll
                for (int r = 0; r < 4; ++r)
                    d4[rt][r] = fast_exp2(fmaf(emc[rt][r], 1.44269504f, -7.0f));

            // per output-column: 8 MFMAs -> row-scale -> repack (no max!)
            #pragma unroll
            for (int ct = 0; ct < 4; ++ct) {
                f32x4 Ct[4];
                #pragma unroll
                for (int tr = 0; tr < 4; ++tr) {
                    f32x4 z = __builtin_amdgcn_mfma_f32_16x16x32_bf16(Ef[tr][0], Bf[0][ct], zero4, 0, 0, 0);
                    z = __builtin_amdgcn_mfma_f32_16x16x32_bf16(Ef[tr][1], Bf[1][ct], z, 0, 0, 0);
                    Ct[tr] = z * d4[tr];
                }
                uint4 q0, q1;
                q0.x = cvtpk_bf16(Ct[0][0], Ct[0][1]);
                q0.y = cvtpk_bf16(Ct[0][2], Ct[0][3]);
                q0.z = cvtpk_bf16(Ct[1][0], Ct[1][1]);
                q0.w = cvtpk_bf16(Ct[1][2], Ct[1][3]);
                q1.x = cvtpk_bf16(Ct[2][0], Ct[2][1]);
                q1.y = cvtpk_bf16(Ct[2][2], Ct[2][3]);
                q1.z = cvtpk_bf16(Ct[3][0], Ct[3][1]);
                q1.w = cvtpk_bf16(Ct[3][2], Ct[3][3]);
                Bf[0][ct] = __builtin_bit_cast(bf16x8, q0);
                Bf[1][ct] = __builtin_bit_cast(bf16x8, q1);
            }
        }
    }

    // ---- ONE-TIME relayout to row-major bf16 Zout via LDS ----
    #pragma unroll
    for (int kt = 0; kt < 2; ++kt)
      #pragma unroll
      for (int ct = 0; ct < 4; ++ct) {
          uint4 q = __builtin_bit_cast(uint4, Bf[kt][ct]);
          int col = 16*ct + c;
          uint2 wa; wa.x = q.x; wa.y = q.y;     // rows 32kt+4gq+0..3
          uint2 wb; wb.x = q.z; wb.y = q.w;     // rows 32kt+16+4gq+0..3
          *(uint2*)&relay[col * 68 + 32*kt      + 4*gq] = wa;
          *(uint2*)&relay[col * 68 + 32*kt + 16 + 4*gq] = wb;
      }
    asm volatile("s_waitcnt lgkmcnt(0)" ::: "memory");

    unsigned short* zo = Zout + ((size_t)(b * GG + g)) * 64 * 64;
    #pragma unroll
    for (int q8 = 0; q8 < 8; ++q8) {
        unsigned dw[4];
        #pragma unroll
        for (int d = 0; d < 4; ++d) {
            unsigned lo = relay[(8*q8 + 2*d    ) * 68 + lane];
            unsigned hi = relay[(8*q8 + 2*d + 1) * 68 + lane];
            dw[d] = lo | (hi << 16);
        }
        uint4 wv; wv.x = dw[0]; wv.y = dw[1]; wv.z = dw[2]; wv.w = dw[3];
        *(uint4*)(zo + (size_t)lane * 64 + 8*q8) = wv;
    }
    if (lane == 0) Kout[b * GG + g] = ktot;
}

// ============================================================================
// Phase 2 (r13/r18-exact): one wave per batch. v <- Z_g v sequentially;
// normalizer = exact pow2 from lane-1's exponent; esum folded at the end.
// ============================================================================
template<int GG>
__global__ __launch_bounds__(64, 1)
void crf_apply(const float* __restrict__ features,
               const int*   __restrict__ labels,
               const float* __restrict__ mask,
               const float* __restrict__ transitions,
               const unsigned short* __restrict__ Zmat,
               const int*   __restrict__ Kscale,
               float*       __restrict__ res)
{
    __shared__ float trans_lds[T * T];
    __shared__ float bcast[2][T];
    const int lane = threadIdx.x;
    const int b = blockIdx.x;

    for (int i = 0; i < T; ++i)
        trans_lds[i * T + lane] = transitions[i * T + lane];
    __syncthreads();

    const float* fb = features + (size_t)b * S * T;
    const int*   lb = labels + (size_t)b * S;
    const float* mb = mask + (size_t)b * S;

    // ---- gold score (lane i handles t = 64*ch + i) ----
    float gold = 0.f;
    #pragma unroll
    for (int ch = 0; ch < S / T; ++ch) {
        int tt = ch * T + lane;
        int tm1 = tt > 0 ? tt - 1 : 0;
        int la = lb[tt], lp = lb[tm1];
        float mt = mb[tt], mp = mb[tm1];
        float em_g = fb[(size_t)tt * T + la];
        float tr_g = trans_lds[lp * T + la];
        gold += em_g * mt + ((tt > 0) ? tr_g * (mp * mt) : 0.f);
    }

    // ---- v init from alpha_0 = em_0, normalized by wave max (one-time) ----
    float a0 = fb[lane];
    float A0 = a0;
    #pragma unroll
    for (int o = 32; o > 0; o >>= 1) A0 = fmaxf(A0, __shfl_xor(A0, o));
    float v = __expf(a0 - A0);

    int esum = 0;

    // double-buffered Z-row loads (lane j holds row j)
    const unsigned short* zb = Zmat + ((size_t)b * GG) * 64 * 64 + (size_t)lane * 64;
    uint4 cur[8], nxt[8];
    #pragma unroll
    for (int i = 0; i < 8; ++i) cur[i] = ((const uint4*)zb)[i];

    for (int g = 0; g < GG; ++g) {
        if (g + 1 < GG) {
            const uint4* zn = (const uint4*)(zb + (size_t)(g + 1) * 64 * 64);
            #pragma unroll
            for (int i = 0; i < 8; ++i) nxt[i] = zn[i];
        }
        const int buf = g & 1;
        bcast[buf][lane] = v;
        asm volatile("s_waitcnt lgkmcnt(0)" ::: "memory");
        f32x4 vb[16];
        #pragma unroll
        for (int q = 0; q < 16; ++q) vb[q] = ((const f32x4*)bcast[buf])[q];

        float ac0 = 0.f, ac1 = 0.f, ac2 = 0.f, ac3 = 0.f;
        #pragma unroll
        for (int i = 0; i < 8; ++i) {
            unsigned zz[4] = {cur[i].x, cur[i].y, cur[i].z, cur[i].w};
            #pragma unroll
            for (int d = 0; d < 4; ++d) {
                int k = i * 8 + d * 2;
                float f0 = __int_as_float(zz[d] << 16);
                float f1 = __int_as_float(zz[d] & 0xFFFF0000u);
                if ((d & 1) == 0) { ac0 = fmaf(f0, vb[k >> 2][k & 3], ac0);
                                    ac1 = fmaf(f1, vb[(k+1) >> 2][(k+1) & 3], ac1); }
                else             { ac2 = fmaf(f0, vb[k >> 2][k & 3], ac2);
                                    ac3 = fmaf(f1, vb[(k+1) >> 2][(k+1) & 3], ac3); }
            }
        }
        float acc = (ac0 + ac1) + (ac2 + ac3);

        // exact pow2 normalizer from lane 1's exponent (lane 0 is PAD -> 0)
        float a1 = fmaxf(rdlane(acc, 1), 1e-30f);
        int e = ((__float_as_int(a1) >> 23) & 0xFF) - 127;
        v = acc * __int_as_float((unsigned)(127 - e) << 23);
        esum += e + Kscale[b * GG + g];

        #pragma unroll
        for (int i = 0; i < 8; ++i) cur[i] = nxt[i];
    }

    float sum = v;
    #pragma unroll
    for (int o = 32; o > 0; o >>= 1) sum += __shfl_xor(sum, o);
    float logZ = __logf(fmaxf(sum, 1e-30f)) + A0 + (float)esum * 0.69314718056f;

    #pragma unroll
    for (int o = 32; o > 0; o >>= 1) gold += __shfl_xor(gold, o);

    if (lane == 0) res[b] = logZ - gold;
}

// ============================================================================
// Fallback: validated round-3 sequential kernel (used if ws too small)
// ============================================================================
__global__ __launch_bounds__(64, 1)
void crf_fwd_seq(const float* __restrict__ features,
                 const int*   __restrict__ labels,
                 const float* __restrict__ mask,
                 const float* __restrict__ transitions,
                 float*       __restrict__ ws)
{
    __shared__ float trans_lds[T * T];
    __shared__ __align__(16) _Float16 ea_lds[2][T];

    const int lane = threadIdx.x;
    const int b    = blockIdx.x;

    for (int i = 0; i < T; ++i)
        trans_lds[i * T + lane] = transitions[i * T + lane];
    __syncthreads();

    h2 etr[T / 2];
    #pragma unroll
    for (int k = 0; k < T / 2; ++k) {
        etr[k].x = (_Float16)__expf(trans_lds[(2 * k + 0) * T + lane]);
        etr[k].y = (_Float16)__expf(trans_lds[(2 * k + 1) * T + lane]);
    }

    const float* fb = features + (size_t)b * S * T;
    const float* mb = mask + (size_t)b * S;
    const int*   lb = labels + (size_t)b * S;

    float alpha = fb[lane];
    float gold_part = 0.f;
    float M = 0.f;

    float em_n1 = fb[1 * T + lane];
    float em_n2 = fb[2 * T + lane];
    float em_n3 = fb[3 * T + lane];

    int   lab_c = lb[lane];
    int   lab_p = lb[lane > 0 ? lane - 1 : 0];
    float m_c   = mb[lane];
    float m_p   = mb[lane > 0 ? lane - 1 : 0];

    for (int ch = 0; ch < S / T; ++ch) {
        const int base = ch * T;
        const int tt   = base + lane;

        const int   glab  = lab_c;
        const int   glabp = lab_p;
        const float gmc   = m_c;
        const float gmp   = m_p;
        const float mreg  = m_c;

        float em_g = fb[(size_t)tt * T + glab];
        float tr_g = trans_lds[glabp * T + glab];

        {
            int tn  = tt + T;  if (tn > S - 1) tn = S - 1;
            int tnp = tn - 1;  if (tnp < 0) tnp = 0;
            lab_c = lb[tn]; lab_p = lb[tnp];
            m_c   = mb[tn]; m_p   = mb[tnp];
        }

        const int i0 = (ch == 0) ? 1 : 0;
        #pragma unroll 4
        for (int i = i0; i < T; ++i) {
            const int t = base + i;
            float em = em_n1;
            em_n1 = em_n2; em_n2 = em_n3;
            int tn = t + 3; if (tn > S - 1) tn = S - 1;
            em_n3 = fb[tn * T + lane];

            float ea = __expf(alpha - M);
            ea_lds[t & 1][lane] = (_Float16)ea;
            asm volatile("s_waitcnt lgkmcnt(0)" ::: "memory");

            const uint4* ep = (const uint4*)&ea_lds[t & 1][0];
            float a0 = 0.f, a1 = 0.f, a2 = 0.f, a3 = 0.f;
            #pragma unroll
            for (int q = 0; q < 8; ++q) {
                uint4 r = ep[q];
                a0 = __builtin_amdgcn_fdot2(__builtin_bit_cast(h2, r.x), etr[4 * q + 0], a0, false);
                a1 = __builtin_amdgcn_fdot2(__builtin_bit_cast(h2, r.y), etr[4 * q + 1], a1, false);
                a2 = __builtin_amdgcn_fdot2(__builtin_bit_cast(h2, r.z), etr[4 * q + 2], a2, false);
                a3 = __builtin_amdgcn_fdot2(__builtin_bit_cast(h2, r.w), etr[4 * q + 3], a3, false);
            }
            float s = (a0 + a1) + (a2 + a3);

            float m_t = rdlane(mreg, i);
            float s1  = rdlane(s, 1);
            float em1 = rdlane(em, 1);
            float Mn  = M + __logf(s1) + em1;

            float val = M + __logf(s) + em;
            val = fmaxf(val, -1e30f);
            alpha = val * m_t + alpha * (1.f - m_t);
            M     = (m_t > 0.5f) ? Mn : M;
        }

        float valid = (tt > 0) ? 1.f : 0.f;
        gold_part += em_g * gmc + tr_g * (gmp * gmc) * valid;
    }

    float M2 = alpha;
    #pragma unroll
    for (int o = 32; o > 0; o >>= 1) M2 = fmaxf(M2, __shfl_xor(M2, o));
    float e2 = __expf(alpha - M2);
    #pragma unroll
    for (int o = 32; o > 0; o >>= 1) e2 += __shfl_xor(e2, o);
    float logZ = M2 + __logf(e2);

    #pragma unroll
    for (int o = 32; o > 0; o >>= 1) gold_part += __shfl_xor(gold_part, o);

    if (lane == 0) ws[b] = logZ - gold_part;
}

// Deterministic final mean over B=128 per-batch results.
__global__ __launch_bounds__(128)
void crf_reduce(const float* __restrict__ ws, float* __restrict__ out)
{
    const int tid = threadIdx.x;
    float v = ws[tid];
    #pragma unroll
    for (int o = 32; o > 0; o >>= 1) v += __shfl_xor(v, o);

    __shared__ float partial[2];
    if ((tid & 63) == 0) partial[tid >> 6] = v;
    __syncthreads();
    if (tid == 0) out[0] = (partial[0] + partial[1]) * (1.0f / (float)B);
}

extern "C" void kernel_launch(void* const* d_in, const int* in_sizes, int n_in,
                              void* d_out, int out_size, void* d_ws, size_t ws_size,
                              hipStream_t stream)
{
    const float* features    = (const float*)d_in[0]; // (B,S,T) f32
    const int*   labels      = (const int*)  d_in[1]; // (B,S) int
    const float* mask        = (const float*)d_in[2]; // (B,S) f32
    const float* transitions = (const float*)d_in[3]; // (T,T) f32
    float* out = (float*)d_out;

    const size_t zbytes = (size_t)B * G * 64 * 64 * sizeof(unsigned short); // 16 MB
    const size_t kbytes = (size_t)B * G * sizeof(int);
    const size_t need   = zbytes + kbytes + (size_t)B * sizeof(float);

    if (ws_size >= need) {
        unsigned short* Zmat = (unsigned short*)d_ws;
        int*   Ks  = (int*)((char*)d_ws + zbytes);
        float* res = (float*)((char*)d_ws + zbytes + kbytes);
        crf_chunk_bf<G><<<dim3(B * G), dim3(64), 0, stream>>>(features, mask, transitions, Zmat, Ks);
        crf_apply<G><<<dim3(B), dim3(64), 0, stream>>>(features, labels, mask, transitions, Zmat, Ks, res);
        crf_reduce<<<dim3(1), dim3(128), 0, stream>>>(res, out);
    } else {
        float* res = (float*)d_ws;
        crf_fwd_seq<<<dim3(B), dim3(64), 0, stream>>>(features, labels, mask, transitions, res);
        crf_reduce<<<dim3(1), dim3(128), 0, stream>>>(res, out);
    }
}